// Round 2
// baseline (825.580 us; speedup 1.0000x reference)
//
#include <hip/hip_runtime.h>

typedef _Float16 f16;
typedef _Float16 f16x2 __attribute__((ext_vector_type(2)));
typedef _Float16 f16x4 __attribute__((ext_vector_type(4)));
typedef _Float16 f16x8 __attribute__((ext_vector_type(8)));
typedef float f32x4 __attribute__((ext_vector_type(4)));

#define N_NODES 50000
#define N_EDGES 600000

// ---------- async global->LDS, 16B per lane ----------
__device__ __forceinline__ void gl_lds16(const void* g, void* l) {
  __builtin_amdgcn_global_load_lds(
      (__attribute__((address_space(1))) void*)(g),
      (__attribute__((address_space(3))) void*)(l), 16, 0, 0);
}

// ---------- merged setup: deg atomics, W transposes, bias pads ----------
// (x->f16 conversion is now fused into gemm1's A-staging)
// grid layout (blocks of 256):
//   [0, 2344)      deg atomics over 600000 edges
//   [2344, 4904)   W1^T  (655360 elems, exact)
//   [4904, 5504)   W2^T  (300 rows x 2 blocks)
//   [5504, 6104)   W3^T padded to 320 (300 rows x 2 blocks)
//   [6104, 6106)   bp2
//   [6106, 6108)   bp3
__global__ void k_setup(const float* __restrict__ W1, f16* __restrict__ w1h,
                        const float* __restrict__ W2, f16* __restrict__ w2h,
                        const float* __restrict__ W3, f16* __restrict__ w3h,
                        const float* __restrict__ b2, float* __restrict__ bp2,
                        const float* __restrict__ b3, float* __restrict__ bp3,
                        const int* __restrict__ edst, int* __restrict__ deg) {
  const int b = blockIdx.x, t = threadIdx.x;
  if (b < 2344) {
    int e = b * 256 + t;
    if (e < N_EDGES) atomicAdd(&deg[edst[e]], 1);
  } else if (b < 4904) {
    int idx = (b - 2344) * 256 + t;        // = n*1280 + k
    int n = idx / 1280, k = idx - n * 1280;
    w1h[idx] = (f16)W1[(size_t)k * 512 + n];
  } else if (b < 5504) {
    int bb = b - 4904;
    int n = bb >> 1, k = (bb & 1) * 256 + t;
    if (k < 512) w2h[(size_t)n * 512 + k] = (f16)W2[(size_t)k * 300 + n];
  } else if (b < 6104) {
    int bb = b - 5504;
    int n = bb >> 1, k = (bb & 1) * 256 + t;
    if (k < 320) w3h[(size_t)n * 320 + k] = (k < 300) ? (f16)W3[(size_t)k * 300 + n] : (f16)0.f;
  } else if (b < 6106) {
    int i = (b - 6104) * 256 + t;
    if (i < 320) bp2[i] = (i < 300) ? b2[i] : 0.f;
  } else {
    int i = (b - 6106) * 256 + t;
    if (i < 320) bp3[i] = (i < 300) ? b3[i] : 0.f;
  }
}

// ---------- multi-block exclusive scan of deg -> rowptr ----------
__device__ __forceinline__ int block_incl_scan256(int v, int t) {
  __shared__ int wsum[4];
  const int lane = t & 63, w = t >> 6;
  int incl = v;
#pragma unroll
  for (int off = 1; off < 64; off <<= 1) {
    int u = __shfl_up(incl, off, 64);
    if (lane >= off) incl += u;
  }
  if (lane == 63) wsum[w] = incl;
  __syncthreads();
  int add = 0;
#pragma unroll
  for (int k = 0; k < 4; ++k)
    if (k < w) add += wsum[k];
  return incl + add;
}

// per-block sums + dinv
__global__ void k_scan1(const int* __restrict__ deg, float* __restrict__ dinv,
                        int* __restrict__ bsum, int n) {
  __shared__ int ws4[4];
  const int t = threadIdx.x, b = blockIdx.x;
  const int i = b * 256 + t;
  int v = (i < n) ? deg[i] : 0;
  if (i < n) dinv[i] = rsqrtf((float)(v + 1));
  int s = v;
#pragma unroll
  for (int off = 1; off < 64; off <<= 1) s += __shfl_xor(s, off, 64);
  if ((t & 63) == 0) ws4[t >> 6] = s;
  __syncthreads();
  if (t == 0) bsum[b] = ws4[0] + ws4[1] + ws4[2] + ws4[3];
}

// scan the 196 block sums (single tiny block) + total -> rowptr[n]
__global__ void k_scan2(const int* __restrict__ bsum, int* __restrict__ bpre,
                        int* __restrict__ rowptr, int nb, int n) {
  const int t = threadIdx.x;
  int v = (t < nb) ? bsum[t] : 0;
  int incl = block_incl_scan256(v, t);
  if (t < nb) bpre[t] = incl - v;
  if (t == 255) rowptr[n] = incl;
}

// full exclusive positions; write rowptr and a second copy used as atomic cursor
__global__ void k_scan3(const int* __restrict__ deg, const int* __restrict__ bpre,
                        int* __restrict__ rowptr, int* __restrict__ rptr2, int n) {
  const int t = threadIdx.x, b = blockIdx.x;
  const int i = b * 256 + t;
  int v = (i < n) ? deg[i] : 0;
  int incl = block_incl_scan256(v, t);
  int ex = bpre[b] + incl - v;
  if (i < n) { rowptr[i] = ex; rptr2[i] = ex; }
}

// fill CSR: meta[pos] = {src, bitcast(norm)}; rptr2 doubles as cursor
__global__ void k_fill(const int* __restrict__ src, const int* __restrict__ dst,
                       int* __restrict__ rptr2, int2* __restrict__ meta,
                       const float* __restrict__ dinv, int E) {
  int e = blockIdx.x * 256 + threadIdx.x;
  if (e < E) {
    int d = dst[e], s = src[e];
    int pos = atomicAdd(&rptr2[d], 1);
    float w = dinv[s] * dinv[d];
    meta[pos] = make_int2(s, __float_as_int(w));
  }
}

// ---------- GEMM (f16 A): C[M,N] = A[M,K] * B^T[N,K], f16 in, f16 out ----------
// 128x128 tile, BK=32, 4 waves (2x2 of 64x64), mfma_f32_16x16x32_f16
// Double-buffered LDS, single barrier per K-iter.
// Grid is (nTilesN, nTilesM): n fastest for A-panel L2 reuse.
// zero-fills C cols in [N, ldc)
__global__ __launch_bounds__(256, 3)
void gemm_f16_tn(const f16* __restrict__ A, const f16* __restrict__ B,
                 f16* __restrict__ C, int M, int N, int K,
                 int lda, int ldb, int ldc) {
  __shared__ __align__(16) f16 As[2][128 * 32];   // 2 x 8 KiB
  __shared__ __align__(16) f16 Bs[2][128 * 32];   // 2 x 8 KiB
  const int tid = threadIdx.x;
  const int wave = tid >> 6;
  const int lane = tid & 63;
  const int bm = blockIdx.y, bn = blockIdx.x;

  const int srow = tid >> 2;
  const int sunit = (tid & 3) ^ ((tid >> 3) & 3);
  long ar0 = (long)bm * 128 + srow;      if (ar0 > M - 1) ar0 = M - 1;
  long ar1 = (long)bm * 128 + srow + 64; if (ar1 > M - 1) ar1 = M - 1;
  long br0 = (long)bn * 128 + srow;      if (br0 > N - 1) br0 = N - 1;
  long br1 = (long)bn * 128 + srow + 64; if (br1 > N - 1) br1 = N - 1;
  const char* aSrc0 = (const char*)(A + ar0 * lda) + sunit * 16;
  const char* aSrc1 = (const char*)(A + ar1 * lda) + sunit * 16;
  const char* bSrc0 = (const char*)(B + br0 * ldb) + sunit * 16;
  const char* bSrc1 = (const char*)(B + br1 * ldb) + sunit * 16;

  const int r16 = lane & 15;
  const int kq = lane >> 4;  // 0..3, k-chunk of 8
  const int wm = wave & 1, wn = wave >> 1;

  int aoff[4], boff[4];
#pragma unroll
  for (int t = 0; t < 4; ++t) {
    int arow = wm * 64 + t * 16 + r16;
    aoff[t] = arow * 64 + ((kq ^ ((arow >> 1) & 3)) << 4);
    int brow = wn * 64 + t * 16 + r16;
    boff[t] = brow * 64 + ((kq ^ ((brow >> 1) & 3)) << 4);
  }

  f32x4 acc[4][4] = {};

  // prologue: stage k0=0 into buf 0
  gl_lds16(aSrc0, (char*)As + wave * 1024);
  gl_lds16(aSrc1, (char*)As + 4096 + wave * 1024);
  gl_lds16(bSrc0, (char*)Bs + wave * 1024);
  gl_lds16(bSrc1, (char*)Bs + 4096 + wave * 1024);
  __syncthreads();

  int buf = 0;
  for (int k0 = 0; k0 < K; k0 += 32) {
    if (k0 + 32 < K) {
      const size_t kb = (size_t)(k0 + 32) * 2;
      const int nb = buf ^ 1;
      gl_lds16(aSrc0 + kb, (char*)As + nb * 8192 + wave * 1024);
      gl_lds16(aSrc1 + kb, (char*)As + nb * 8192 + 4096 + wave * 1024);
      gl_lds16(bSrc0 + kb, (char*)Bs + nb * 8192 + wave * 1024);
      gl_lds16(bSrc1 + kb, (char*)Bs + nb * 8192 + 4096 + wave * 1024);
    }

    const char* baseA = (const char*)As + buf * 8192;
    const char* baseB = (const char*)Bs + buf * 8192;
    f16x8 af[4], bf[4];
#pragma unroll
    for (int t = 0; t < 4; ++t) {
      af[t] = *(const f16x8*)(baseA + aoff[t]);
      bf[t] = *(const f16x8*)(baseB + boff[t]);
    }
#pragma unroll
    for (int mt = 0; mt < 4; ++mt)
#pragma unroll
      for (int nt = 0; nt < 4; ++nt)
        acc[mt][nt] = __builtin_amdgcn_mfma_f32_16x16x32_f16(af[mt], bf[nt], acc[mt][nt], 0, 0, 0);

    __syncthreads();
    buf ^= 1;
  }

  const int crow0 = bm * 128 + wm * 64;
  const int ccol0 = bn * 128 + wn * 64;
#pragma unroll
  for (int mt = 0; mt < 4; ++mt)
#pragma unroll
    for (int nt = 0; nt < 4; ++nt)
#pragma unroll
      for (int r = 0; r < 4; ++r) {
        int row = crow0 + mt * 16 + kq * 4 + r;
        int col = ccol0 + nt * 16 + r16;
        if (row < M && col < ldc)
          C[(size_t)row * ldc + col] = (col < N) ? (f16)acc[mt][nt][r] : (f16)0.f;
      }
}

// ---------- GEMM (fp32 A, fused convert): C = A32[M,K] * B^T[N,K] ----------
// Same tile/layout as gemm_f16_tn, but A is fp32 in HBM: reg-stage 2x float4
// per half-tile per thread, convert to f16x8, ds_write into the identical
// swizzled LDS layout (T14: loads issued before MFMA, writes after).
__global__ __launch_bounds__(256, 2)
void gemm_f32a_tn(const float* __restrict__ A, const f16* __restrict__ B,
                  f16* __restrict__ C, int M, int N, int K,
                  int lda, int ldb, int ldc) {
  __shared__ __align__(16) f16 As[2][128 * 32];
  __shared__ __align__(16) f16 Bs[2][128 * 32];
  const int tid = threadIdx.x;
  const int wave = tid >> 6;
  const int lane = tid & 63;
  const int bm = blockIdx.y, bn = blockIdx.x;

  const int srow = tid >> 2;
  const int sunit = (tid & 3) ^ ((tid >> 3) & 3);
  long ar0 = (long)bm * 128 + srow;      if (ar0 > M - 1) ar0 = M - 1;
  long ar1 = (long)bm * 128 + srow + 64; if (ar1 > M - 1) ar1 = M - 1;
  long br0 = (long)bn * 128 + srow;      if (br0 > N - 1) br0 = N - 1;
  long br1 = (long)bn * 128 + srow + 64; if (br1 > N - 1) br1 = N - 1;
  const float* aP0 = A + ar0 * lda + sunit * 8;   // 8 floats = one f16x8 unit
  const float* aP1 = A + ar1 * lda + sunit * 8;
  const char* bSrc0 = (const char*)(B + br0 * ldb) + sunit * 16;
  const char* bSrc1 = (const char*)(B + br1 * ldb) + sunit * 16;

  const int r16 = lane & 15;
  const int kq = lane >> 4;
  const int wm = wave & 1, wn = wave >> 1;

  int aoff[4], boff[4];
#pragma unroll
  for (int t = 0; t < 4; ++t) {
    int arow = wm * 64 + t * 16 + r16;
    aoff[t] = arow * 64 + ((kq ^ ((arow >> 1) & 3)) << 4);
    int brow = wn * 64 + t * 16 + r16;
    boff[t] = brow * 64 + ((kq ^ ((brow >> 1) & 3)) << 4);
  }

  f32x4 acc[4][4] = {};

  // prologue: stage tile k0=0
  {
    float4 u0 = *(const float4*)(aP0);
    float4 u1 = *(const float4*)(aP0 + 4);
    float4 v0 = *(const float4*)(aP1);
    float4 v1 = *(const float4*)(aP1 + 4);
    f16x8 a0, a1;
    a0[0]=(f16)u0.x; a0[1]=(f16)u0.y; a0[2]=(f16)u0.z; a0[3]=(f16)u0.w;
    a0[4]=(f16)u1.x; a0[5]=(f16)u1.y; a0[6]=(f16)u1.z; a0[7]=(f16)u1.w;
    a1[0]=(f16)v0.x; a1[1]=(f16)v0.y; a1[2]=(f16)v0.z; a1[3]=(f16)v0.w;
    a1[4]=(f16)v1.x; a1[5]=(f16)v1.y; a1[6]=(f16)v1.z; a1[7]=(f16)v1.w;
    *(f16x8*)((char*)As + tid * 16) = a0;
    *(f16x8*)((char*)As + 4096 + tid * 16) = a1;
    gl_lds16(bSrc0, (char*)Bs + wave * 1024);
    gl_lds16(bSrc1, (char*)Bs + 4096 + wave * 1024);
  }
  __syncthreads();

  int buf = 0;
  for (int k0 = 0; k0 < K; k0 += 32) {
    const bool next = (k0 + 32 < K);
    float4 u0, u1, v0, v1;
    if (next) {
      // issue next A-tile loads early (hide HBM latency under MFMAs)
      u0 = *(const float4*)(aP0 + k0 + 32);
      u1 = *(const float4*)(aP0 + k0 + 36);
      v0 = *(const float4*)(aP1 + k0 + 32);
      v1 = *(const float4*)(aP1 + k0 + 36);
      const size_t kb = (size_t)(k0 + 32) * 2;
      const int nb = buf ^ 1;
      gl_lds16(bSrc0 + kb, (char*)Bs + nb * 8192 + wave * 1024);
      gl_lds16(bSrc1 + kb, (char*)Bs + nb * 8192 + 4096 + wave * 1024);
    }

    const char* baseA = (const char*)As + buf * 8192;
    const char* baseB = (const char*)Bs + buf * 8192;
    f16x8 af[4], bf[4];
#pragma unroll
    for (int t = 0; t < 4; ++t) {
      af[t] = *(const f16x8*)(baseA + aoff[t]);
      bf[t] = *(const f16x8*)(baseB + boff[t]);
    }
#pragma unroll
    for (int mt = 0; mt < 4; ++mt)
#pragma unroll
      for (int nt = 0; nt < 4; ++nt)
        acc[mt][nt] = __builtin_amdgcn_mfma_f32_16x16x32_f16(af[mt], bf[nt], acc[mt][nt], 0, 0, 0);

    if (next) {
      // convert + write next A-tile (write-late half of T14 split)
      const int nb = buf ^ 1;
      f16x8 a0, a1;
      a0[0]=(f16)u0.x; a0[1]=(f16)u0.y; a0[2]=(f16)u0.z; a0[3]=(f16)u0.w;
      a0[4]=(f16)u1.x; a0[5]=(f16)u1.y; a0[6]=(f16)u1.z; a0[7]=(f16)u1.w;
      a1[0]=(f16)v0.x; a1[1]=(f16)v0.y; a1[2]=(f16)v0.z; a1[3]=(f16)v0.w;
      a1[4]=(f16)v1.x; a1[5]=(f16)v1.y; a1[6]=(f16)v1.z; a1[7]=(f16)v1.w;
      *(f16x8*)((char*)As + nb * 8192 + tid * 16) = a0;
      *(f16x8*)((char*)As + nb * 8192 + 4096 + tid * 16) = a1;
    }

    __syncthreads();
    buf ^= 1;
  }

  const int crow0 = bm * 128 + wm * 64;
  const int ccol0 = bn * 128 + wn * 64;
#pragma unroll
  for (int mt = 0; mt < 4; ++mt)
#pragma unroll
    for (int nt = 0; nt < 4; ++nt)
#pragma unroll
      for (int r = 0; r < 4; ++r) {
        int row = crow0 + mt * 16 + kq * 4 + r;
        int col = ccol0 + nt * 16 + r16;
        if (row < M && col < ldc)
          C[(size_t)row * ldc + col] = (col < N) ? (f16)acc[mt][nt][r] : (f16)0.f;
      }
}

// ---------- aggregation v3: wave-per-node, coalesced meta prefetch + shuffle bcast ----------
// out[n] = relu( dinv[n]^2*h[n] + sum_e w[e]*h[src[e]] + b )
template <int LDH, int ACT, bool F16OUT, int DOUT>
__global__ __launch_bounds__(256, 8)
void agg_relu3(const f16* __restrict__ h, const int* __restrict__ rowptr,
               const int2* __restrict__ meta, const float* __restrict__ dinv,
               const float* __restrict__ bias, void* __restrict__ outp, int nNodes) {
  const int tid = threadIdx.x;
  const int lane = tid & 63;
  const int node = blockIdx.x * 4 + (tid >> 6);
  if (node >= nNodes) return;
  const int r0 = __builtin_amdgcn_readfirstlane(rowptr[node]);
  const int r1 = __builtin_amdgcn_readfirstlane(rowptr[node + 1]);
  const float dv = __builtin_bit_cast(
      float, __builtin_amdgcn_readfirstlane(__builtin_bit_cast(int, dinv[node])));

  const int hoff = (lane < ACT ? lane : ACT - 1) * 8;
  const f16* hp = h + hoff;

  float acc[8];
  {
    f16x8 v = *(const f16x8*)(hp + (size_t)node * LDH);
    const float w0 = dv * dv;
#pragma unroll
    for (int j = 0; j < 8; ++j) acc[j] = w0 * (float)v[j];
  }

  for (int base = r0; base < r1; base += 64) {
    const int idx = base + lane;
    int2 m = (idx < r1) ? meta[idx] : make_int2(0, 0);
    const int cnt = min(64, r1 - base);
    int j = 0;
    for (; j + 2 <= cnt; j += 2) {
      int s0 = __shfl(m.x, j, 64);
      int s1 = __shfl(m.x, j + 1, 64);
      float w0 = __int_as_float(__shfl(m.y, j, 64));
      float w1 = __int_as_float(__shfl(m.y, j + 1, 64));
      f16x8 v0 = *(const f16x8*)(hp + (size_t)s0 * LDH);
      f16x8 v1 = *(const f16x8*)(hp + (size_t)s1 * LDH);
#pragma unroll
      for (int q = 0; q < 8; ++q) acc[q] = fmaf(w0, (float)v0[q], acc[q]);
#pragma unroll
      for (int q = 0; q < 8; ++q) acc[q] = fmaf(w1, (float)v1[q], acc[q]);
    }
    if (j < cnt) {
      int s0 = __shfl(m.x, j, 64);
      float w0 = __int_as_float(__shfl(m.y, j, 64));
      f16x8 v0 = *(const f16x8*)(hp + (size_t)s0 * LDH);
#pragma unroll
      for (int q = 0; q < 8; ++q) acc[q] = fmaf(w0, (float)v0[q], acc[q]);
    }
  }

  float4 bv0 = *(const float4*)(bias + hoff);
  float4 bv1 = *(const float4*)(bias + hoff + 4);
  float o[8];
  o[0] = fmaxf(acc[0] + bv0.x, 0.f); o[1] = fmaxf(acc[1] + bv0.y, 0.f);
  o[2] = fmaxf(acc[2] + bv0.z, 0.f); o[3] = fmaxf(acc[3] + bv0.w, 0.f);
  o[4] = fmaxf(acc[4] + bv1.x, 0.f); o[5] = fmaxf(acc[5] + bv1.y, 0.f);
  o[6] = fmaxf(acc[6] + bv1.z, 0.f); o[7] = fmaxf(acc[7] + bv1.w, 0.f);

  if constexpr (F16OUT) {
    if (lane < ACT) {
      f16x8 ov;
#pragma unroll
      for (int j = 0; j < 8; ++j) ov[j] = (f16)o[j];
      *(f16x8*)((f16*)outp + (size_t)node * LDH + lane * 8) = ov;
    }
  } else {
    float* orow = (float*)outp + (size_t)node * DOUT + lane * 8;
    if (lane * 8 + 4 <= DOUT)
      *(float4*)(orow) = make_float4(o[0], o[1], o[2], o[3]);
    if (lane * 8 + 8 <= DOUT)
      *(float4*)(orow + 4) = make_float4(o[4], o[5], o[6], o[7]);
  }
}

extern "C" void kernel_launch(void* const* d_in, const int* in_sizes, int n_in,
                              void* d_out, int out_size, void* d_ws, size_t ws_size,
                              hipStream_t stream) {
  const float* x  = (const float*)d_in[0];
  const float* W1 = (const float*)d_in[1];
  const float* b1 = (const float*)d_in[2];
  const float* W2 = (const float*)d_in[3];
  const float* b2 = (const float*)d_in[4];
  const float* W3 = (const float*)d_in[5];
  const float* b3 = (const float*)d_in[6];
  const int* eidx = (const int*)d_in[7];
  const int* esrc = eidx;
  const int* edst = eidx + N_EDGES;
  float* out = (float*)d_out;

  char* ws = (char*)d_ws;
  f16* h2 = (f16*)(ws);                      // 50000*320*2  =  32,000,000
  f16* g2 = (f16*)(ws + 32000000);           // 32,000,000
  f16* h3 = (f16*)(ws + 64000000);           // 32,000,000
  f16* h1 = (f16*)(ws + 128000000);          // 50000*512*2  =  51,200,000
  f16* g1 = (f16*)(ws + 179200000);          // 51,200,000
  f16* w1h = (f16*)(ws + 230400000);         // 1,310,720
  f16* w2h = (f16*)(ws + 231710720);         //   307,200
  f16* w3h = (f16*)(ws + 232017920);         //   192,000
  float* bp2 = (float*)(ws + 232209920);     //     1,280
  float* bp3 = (float*)(ws + 232211200);     //     1,280
  int* deg    = (int*)(ws + 232212480);      //   200,000
  float* dinv = (float*)(ws + 232412480);    //   200,000
  int* rowptr = (int*)(ws + 232612480);      //   200,004
  int* rptr2  = (int*)(ws + 232812484);      //   200,004
  int* bsum   = (int*)(ws + 233012488);      //       800
  int* bpre   = (int*)(ws + 233013288);      //       800
  int2* meta  = (int2*)(ws + 233014088);     // 4,800,000 -> total 237,814,088

  hipMemsetAsync(deg, 0, N_NODES * sizeof(int), stream);

  // merged setup: deg atomics + W^T + bias pads (x convert fused into gemm1)
  k_setup<<<6108, 256, 0, stream>>>(W1, w1h, W2, w2h, W3, w3h,
                                    b2, bp2, b3, bp3, edst, deg);

  // multi-block scan + dinv
  k_scan1<<<196, 256, 0, stream>>>(deg, dinv, bsum, N_NODES);
  k_scan2<<<1, 256, 0, stream>>>(bsum, bpre, rowptr, 196, N_NODES);
  k_scan3<<<196, 256, 0, stream>>>(deg, bpre, rowptr, rptr2, N_NODES);
  k_fill<<<2344, 256, 0, stream>>>(esrc, edst, rptr2, meta, dinv, N_EDGES);

  // layer 1: h1 = cvt16(x) @ W1 ; g1 = relu(agg(h1) + b1)  (fp32-A fused GEMM)
  gemm_f32a_tn<<<dim3(4, 391), 256, 0, stream>>>(x, w1h, h1, N_NODES, 512, 1280, 1280, 1280, 512);
  agg_relu3<512, 64, true, 0><<<12500, 256, 0, stream>>>(h1, rowptr, meta, dinv, b1, g1, N_NODES);

  // layer 2: h2 = g1 @ W2 (ldc=320, pad zeroed) ; g2 = relu(agg(h2) + bp2)
  gemm_f16_tn<<<dim3(3, 391), 256, 0, stream>>>(g1, w2h, h2, N_NODES, 300, 512, 512, 512, 320);
  agg_relu3<320, 40, true, 0><<<12500, 256, 0, stream>>>(h2, rowptr, meta, dinv, bp2, g2, N_NODES);

  // layer 3: h3 = g2 @ W3 (K=320 padded) ; out = relu(agg(h3) + bp3) fp32
  gemm_f16_tn<<<dim3(3, 391), 256, 0, stream>>>(g2, w3h, h3, N_NODES, 300, 320, 320, 320, 320);
  agg_relu3<320, 38, false, 300><<<12500, 256, 0, stream>>>(h3, rowptr, meta, dinv, bp3, out, N_NODES);
}

// Round 3
// 819.515 us; speedup vs baseline: 1.0074x; 1.0074x over previous
//
#include <hip/hip_runtime.h>

typedef _Float16 f16;
typedef _Float16 f16x2 __attribute__((ext_vector_type(2)));
typedef _Float16 f16x4 __attribute__((ext_vector_type(4)));
typedef _Float16 f16x8 __attribute__((ext_vector_type(8)));
typedef float f32x4 __attribute__((ext_vector_type(4)));

#define N_NODES 50000
#define N_EDGES 600000

// ---------- async global->LDS, 16B per lane ----------
__device__ __forceinline__ void gl_lds16(const void* g, void* l) {
  __builtin_amdgcn_global_load_lds(
      (__attribute__((address_space(1))) void*)(g),
      (__attribute__((address_space(3))) void*)(l), 16, 0, 0);
}

// ---------- merged setup: x->f16, deg atomics, W transposes, bias pads ----------
// grid layout (blocks of 256):
//   [0, 62500)        x convert (50000*1280/4 float4s, exact)
//   [62500, 64844)    deg atomics over 600000 edges
//   [64844, 67404)    W1^T  (655360 elems, exact)
//   [67404, 68004)    W2^T  (300 rows x 2 blocks)
//   [68004, 68604)    W3^T padded to 320 (300 rows x 2 blocks)
//   [68604, 68606)    bp2
//   [68606, 68608)    bp3
__global__ void k_setup(const float* __restrict__ x, f16* __restrict__ xh,
                        const float* __restrict__ W1, f16* __restrict__ w1h,
                        const float* __restrict__ W2, f16* __restrict__ w2h,
                        const float* __restrict__ W3, f16* __restrict__ w3h,
                        const float* __restrict__ b2, float* __restrict__ bp2,
                        const float* __restrict__ b3, float* __restrict__ bp3,
                        const int* __restrict__ edst, int* __restrict__ deg) {
  const int b = blockIdx.x, t = threadIdx.x;
  if (b < 62500) {
    long i = (long)b * 256 + t;
    float4 v = ((const float4*)x)[i];
    f16x4 o;
    o[0] = (f16)v.x; o[1] = (f16)v.y; o[2] = (f16)v.z; o[3] = (f16)v.w;
    ((f16x4*)xh)[i] = o;
  } else if (b < 64844) {
    int e = (b - 62500) * 256 + t;
    if (e < N_EDGES) atomicAdd(&deg[edst[e]], 1);
  } else if (b < 67404) {
    int idx = (b - 64844) * 256 + t;       // = n*1280 + k
    int n = idx / 1280, k = idx - n * 1280;
    w1h[idx] = (f16)W1[(size_t)k * 512 + n];
  } else if (b < 68004) {
    int bb = b - 67404;
    int n = bb >> 1, k = (bb & 1) * 256 + t;
    if (k < 512) w2h[(size_t)n * 512 + k] = (f16)W2[(size_t)k * 300 + n];
  } else if (b < 68604) {
    int bb = b - 68004;
    int n = bb >> 1, k = (bb & 1) * 256 + t;
    if (k < 320) w3h[(size_t)n * 320 + k] = (k < 300) ? (f16)W3[(size_t)k * 300 + n] : (f16)0.f;
  } else if (b < 68606) {
    int i = (b - 68604) * 256 + t;
    if (i < 320) bp2[i] = (i < 300) ? b2[i] : 0.f;
  } else {
    int i = (b - 68606) * 256 + t;
    if (i < 320) bp3[i] = (i < 300) ? b3[i] : 0.f;
  }
}

// ---------- multi-block exclusive scan of deg -> rowptr ----------
__device__ __forceinline__ int block_incl_scan256(int v, int t) {
  __shared__ int wsum[4];
  const int lane = t & 63, w = t >> 6;
  int incl = v;
#pragma unroll
  for (int off = 1; off < 64; off <<= 1) {
    int u = __shfl_up(incl, off, 64);
    if (lane >= off) incl += u;
  }
  if (lane == 63) wsum[w] = incl;
  __syncthreads();
  int add = 0;
#pragma unroll
  for (int k = 0; k < 4; ++k)
    if (k < w) add += wsum[k];
  return incl + add;
}

// per-block sums + dinv
__global__ void k_scan1(const int* __restrict__ deg, float* __restrict__ dinv,
                        int* __restrict__ bsum, int n) {
  __shared__ int ws4[4];
  const int t = threadIdx.x, b = blockIdx.x;
  const int i = b * 256 + t;
  int v = (i < n) ? deg[i] : 0;
  if (i < n) dinv[i] = rsqrtf((float)(v + 1));
  int s = v;
#pragma unroll
  for (int off = 1; off < 64; off <<= 1) s += __shfl_xor(s, off, 64);
  if ((t & 63) == 0) ws4[t >> 6] = s;
  __syncthreads();
  if (t == 0) bsum[b] = ws4[0] + ws4[1] + ws4[2] + ws4[3];
}

// scan the 196 block sums (single tiny block) + total -> rowptr[n]
__global__ void k_scan2(const int* __restrict__ bsum, int* __restrict__ bpre,
                        int* __restrict__ rowptr, int nb, int n) {
  const int t = threadIdx.x;
  int v = (t < nb) ? bsum[t] : 0;
  int incl = block_incl_scan256(v, t);
  if (t < nb) bpre[t] = incl - v;
  if (t == 255) rowptr[n] = incl;
}

// full exclusive positions; write rowptr and a second copy used as atomic cursor
__global__ void k_scan3(const int* __restrict__ deg, const int* __restrict__ bpre,
                        int* __restrict__ rowptr, int* __restrict__ rptr2, int n) {
  const int t = threadIdx.x, b = blockIdx.x;
  const int i = b * 256 + t;
  int v = (i < n) ? deg[i] : 0;
  int incl = block_incl_scan256(v, t);
  int ex = bpre[b] + incl - v;
  if (i < n) { rowptr[i] = ex; rptr2[i] = ex; }
}

// fill CSR: meta[pos] = {src, bitcast(norm)}; rptr2 doubles as cursor
__global__ void k_fill(const int* __restrict__ src, const int* __restrict__ dst,
                       int* __restrict__ rptr2, int2* __restrict__ meta,
                       const float* __restrict__ dinv, int E) {
  int e = blockIdx.x * 256 + threadIdx.x;
  if (e < E) {
    int d = dst[e], s = src[e];
    int pos = atomicAdd(&rptr2[d], 1);
    float w = dinv[s] * dinv[d];
    meta[pos] = make_int2(s, __float_as_int(w));
  }
}

// ---------- GEMM: C[M,N] = A[M,K] * B^T[N,K], f16 in, f16 out ----------
// 128x128 tile, BK=32, 4 waves (2x2 of 64x64), mfma_f32_16x16x32_f16
// TRIPLE-buffered LDS, prefetch depth 2, COUNTED vmcnt (T3+T4 recipe):
//   iter t top: s_waitcnt vmcnt(4)  -> tile t's 4 loads done, tile t+1's 4
//               stay in flight across the raw s_barrier; then issue tile t+2.
// Never drains vmcnt to 0 in the main loop -> HBM latency spans 2 iterations.
// Safety: vmcnt(4)+barrier publishes tile t to all waves; each wave's ds_reads
// of buf (t-1)%3 are consumed by its MFMAs (compiler lgkmcnt) before it
// reaches the next barrier, so the overwrite (t+2)%3 == (t-1)%3 is ordered.
// zero-fills C cols in [N, ldc)
__global__ __launch_bounds__(256, 3)
void gemm_f16_tn(const f16* __restrict__ A, const f16* __restrict__ B,
                 f16* __restrict__ C, int M, int N, int K,
                 int lda, int ldb, int ldc) {
  __shared__ __align__(16) f16 As[3][128 * 32];   // 3 x 8 KiB
  __shared__ __align__(16) f16 Bs[3][128 * 32];   // 3 x 8 KiB  (48 KiB total)
  const int tid = threadIdx.x;
  const int wave = tid >> 6;
  const int lane = tid & 63;
  const int bm = blockIdx.y, bn = blockIdx.x;

  const int srow = tid >> 2;
  const int sunit = (tid & 3) ^ ((tid >> 3) & 3);
  long ar0 = (long)bm * 128 + srow;      if (ar0 > M - 1) ar0 = M - 1;
  long ar1 = (long)bm * 128 + srow + 64; if (ar1 > M - 1) ar1 = M - 1;
  long br0 = (long)bn * 128 + srow;      if (br0 > N - 1) br0 = N - 1;
  long br1 = (long)bn * 128 + srow + 64; if (br1 > N - 1) br1 = N - 1;
  const char* aSrc0 = (const char*)(A + ar0 * lda) + sunit * 16;
  const char* aSrc1 = (const char*)(A + ar1 * lda) + sunit * 16;
  const char* bSrc0 = (const char*)(B + br0 * ldb) + sunit * 16;
  const char* bSrc1 = (const char*)(B + br1 * ldb) + sunit * 16;
  char* const ldsA = (char*)As + wave * 1024;   // + buf*8192 (+4096 half 1)
  char* const ldsB = (char*)Bs + wave * 1024;

  const int r16 = lane & 15;
  const int kq = lane >> 4;  // 0..3, k-chunk of 8
  const int wm = wave & 1, wn = wave >> 1;

  int aoff[4], boff[4];
#pragma unroll
  for (int t = 0; t < 4; ++t) {
    int arow = wm * 64 + t * 16 + r16;
    aoff[t] = arow * 64 + ((kq ^ ((arow >> 1) & 3)) << 4);
    int brow = wn * 64 + t * 16 + r16;
    boff[t] = brow * 64 + ((kq ^ ((brow >> 1) & 3)) << 4);
  }

  f32x4 acc[4][4] = {};
  const int nt = K >> 5;   // K is a multiple of 32 for all call sites

  // prologue: stage tiles 0 and 1 into bufs 0 and 1  (8 loads/wave in flight)
  gl_lds16(aSrc0, ldsA);
  gl_lds16(aSrc1, ldsA + 4096);
  gl_lds16(bSrc0, ldsB);
  gl_lds16(bSrc1, ldsB + 4096);
  gl_lds16(aSrc0 + 64, ldsA + 8192);
  gl_lds16(aSrc1 + 64, ldsA + 8192 + 4096);
  gl_lds16(bSrc0 + 64, ldsB + 8192);
  gl_lds16(bSrc1 + 64, ldsB + 8192 + 4096);

  int buf = 0;
  for (int t = 0; t < nt - 1; ++t) {
    // tile t ready once <=4 loads outstanding (the newest 4 = tile t+1's)
    asm volatile("s_waitcnt vmcnt(4)" ::: "memory");
    __builtin_amdgcn_sched_barrier(0);
    __builtin_amdgcn_s_barrier();
    __builtin_amdgcn_sched_barrier(0);

    if (t + 2 < nt) {
      const size_t kb = (size_t)(t + 2) * 64;   // 32 k * 2 B
      int nbuf = buf + 2; if (nbuf >= 3) nbuf -= 3;
      char* dA = (char*)As + nbuf * 8192 + wave * 1024;
      char* dB = (char*)Bs + nbuf * 8192 + wave * 1024;
      gl_lds16(aSrc0 + kb, dA);
      gl_lds16(aSrc1 + kb, dA + 4096);
      gl_lds16(bSrc0 + kb, dB);
      gl_lds16(bSrc1 + kb, dB + 4096);
    }

    const char* baseA = (const char*)As + buf * 8192;
    const char* baseB = (const char*)Bs + buf * 8192;
    f16x8 af[4], bf[4];
#pragma unroll
    for (int q = 0; q < 4; ++q) {
      af[q] = *(const f16x8*)(baseA + aoff[q]);
      bf[q] = *(const f16x8*)(baseB + boff[q]);
    }
#pragma unroll
    for (int mt = 0; mt < 4; ++mt)
#pragma unroll
      for (int nt2 = 0; nt2 < 4; ++nt2)
        acc[mt][nt2] = __builtin_amdgcn_mfma_f32_16x16x32_f16(af[mt], bf[nt2], acc[mt][nt2], 0, 0, 0);

    buf = (buf + 1 == 3) ? 0 : buf + 1;
  }

  // final tile: drain everything
  asm volatile("s_waitcnt vmcnt(0)" ::: "memory");
  __builtin_amdgcn_sched_barrier(0);
  __builtin_amdgcn_s_barrier();
  __builtin_amdgcn_sched_barrier(0);
  {
    const char* baseA = (const char*)As + buf * 8192;
    const char* baseB = (const char*)Bs + buf * 8192;
    f16x8 af[4], bf[4];
#pragma unroll
    for (int q = 0; q < 4; ++q) {
      af[q] = *(const f16x8*)(baseA + aoff[q]);
      bf[q] = *(const f16x8*)(baseB + boff[q]);
    }
#pragma unroll
    for (int mt = 0; mt < 4; ++mt)
#pragma unroll
      for (int nt2 = 0; nt2 < 4; ++nt2)
        acc[mt][nt2] = __builtin_amdgcn_mfma_f32_16x16x32_f16(af[mt], bf[nt2], acc[mt][nt2], 0, 0, 0);
  }

  const int crow0 = bm * 128 + wm * 64;
  const int ccol0 = bn * 128 + wn * 64;
#pragma unroll
  for (int mt = 0; mt < 4; ++mt)
#pragma unroll
    for (int nt2 = 0; nt2 < 4; ++nt2)
#pragma unroll
      for (int r = 0; r < 4; ++r) {
        int row = crow0 + mt * 16 + kq * 4 + r;
        int col = ccol0 + nt2 * 16 + r16;
        if (row < M && col < ldc)
          C[(size_t)row * ldc + col] = (col < N) ? (f16)acc[mt][nt2][r] : (f16)0.f;
      }
}

// ---------- aggregation v3: wave-per-node, coalesced meta prefetch + shuffle bcast ----------
// out[n] = relu( dinv[n]^2*h[n] + sum_e w[e]*h[src[e]] + b )
template <int LDH, int ACT, bool F16OUT, int DOUT>
__global__ __launch_bounds__(256, 8)
void agg_relu3(const f16* __restrict__ h, const int* __restrict__ rowptr,
               const int2* __restrict__ meta, const float* __restrict__ dinv,
               const float* __restrict__ bias, void* __restrict__ outp, int nNodes) {
  const int tid = threadIdx.x;
  const int lane = tid & 63;
  const int node = blockIdx.x * 4 + (tid >> 6);
  if (node >= nNodes) return;
  const int r0 = __builtin_amdgcn_readfirstlane(rowptr[node]);
  const int r1 = __builtin_amdgcn_readfirstlane(rowptr[node + 1]);
  const float dv = __builtin_bit_cast(
      float, __builtin_amdgcn_readfirstlane(__builtin_bit_cast(int, dinv[node])));

  const int hoff = (lane < ACT ? lane : ACT - 1) * 8;
  const f16* hp = h + hoff;

  float acc[8];
  {
    f16x8 v = *(const f16x8*)(hp + (size_t)node * LDH);
    const float w0 = dv * dv;
#pragma unroll
    for (int j = 0; j < 8; ++j) acc[j] = w0 * (float)v[j];
  }

  for (int base = r0; base < r1; base += 64) {
    const int idx = base + lane;
    int2 m = (idx < r1) ? meta[idx] : make_int2(0, 0);
    const int cnt = min(64, r1 - base);
    int j = 0;
    for (; j + 2 <= cnt; j += 2) {
      int s0 = __shfl(m.x, j, 64);
      int s1 = __shfl(m.x, j + 1, 64);
      float w0 = __int_as_float(__shfl(m.y, j, 64));
      float w1 = __int_as_float(__shfl(m.y, j + 1, 64));
      f16x8 v0 = *(const f16x8*)(hp + (size_t)s0 * LDH);
      f16x8 v1 = *(const f16x8*)(hp + (size_t)s1 * LDH);
#pragma unroll
      for (int q = 0; q < 8; ++q) acc[q] = fmaf(w0, (float)v0[q], acc[q]);
#pragma unroll
      for (int q = 0; q < 8; ++q) acc[q] = fmaf(w1, (float)v1[q], acc[q]);
    }
    if (j < cnt) {
      int s0 = __shfl(m.x, j, 64);
      float w0 = __int_as_float(__shfl(m.y, j, 64));
      f16x8 v0 = *(const f16x8*)(hp + (size_t)s0 * LDH);
#pragma unroll
      for (int q = 0; q < 8; ++q) acc[q] = fmaf(w0, (float)v0[q], acc[q]);
    }
  }

  float4 bv0 = *(const float4*)(bias + hoff);
  float4 bv1 = *(const float4*)(bias + hoff + 4);
  float o[8];
  o[0] = fmaxf(acc[0] + bv0.x, 0.f); o[1] = fmaxf(acc[1] + bv0.y, 0.f);
  o[2] = fmaxf(acc[2] + bv0.z, 0.f); o[3] = fmaxf(acc[3] + bv0.w, 0.f);
  o[4] = fmaxf(acc[4] + bv1.x, 0.f); o[5] = fmaxf(acc[5] + bv1.y, 0.f);
  o[6] = fmaxf(acc[6] + bv1.z, 0.f); o[7] = fmaxf(acc[7] + bv1.w, 0.f);

  if constexpr (F16OUT) {
    if (lane < ACT) {
      f16x8 ov;
#pragma unroll
      for (int j = 0; j < 8; ++j) ov[j] = (f16)o[j];
      *(f16x8*)((f16*)outp + (size_t)node * LDH + lane * 8) = ov;
    }
  } else {
    float* orow = (float*)outp + (size_t)node * DOUT + lane * 8;
    if (lane * 8 + 4 <= DOUT)
      *(float4*)(orow) = make_float4(o[0], o[1], o[2], o[3]);
    if (lane * 8 + 8 <= DOUT)
      *(float4*)(orow + 4) = make_float4(o[4], o[5], o[6], o[7]);
  }
}

extern "C" void kernel_launch(void* const* d_in, const int* in_sizes, int n_in,
                              void* d_out, int out_size, void* d_ws, size_t ws_size,
                              hipStream_t stream) {
  const float* x  = (const float*)d_in[0];
  const float* W1 = (const float*)d_in[1];
  const float* b1 = (const float*)d_in[2];
  const float* W2 = (const float*)d_in[3];
  const float* b2 = (const float*)d_in[4];
  const float* W3 = (const float*)d_in[5];
  const float* b3 = (const float*)d_in[6];
  const int* eidx = (const int*)d_in[7];
  const int* esrc = eidx;
  const int* edst = eidx + N_EDGES;
  float* out = (float*)d_out;

  char* ws = (char*)d_ws;
  f16* xh = (f16*)(ws);                      // 50000*1280*2 = 128,000,000
  f16* h2 = (f16*)(ws);                      // 50000*320*2  =  32,000,000
  f16* g2 = (f16*)(ws + 32000000);           // 32,000,000
  f16* h3 = (f16*)(ws + 64000000);           // 32,000,000
  f16* h1 = (f16*)(ws + 128000000);          // 50000*512*2  =  51,200,000
  f16* g1 = (f16*)(ws + 179200000);          // 51,200,000
  f16* w1h = (f16*)(ws + 230400000);         // 1,310,720
  f16* w2h = (f16*)(ws + 231710720);         //   307,200
  f16* w3h = (f16*)(ws + 232017920);         //   192,000
  float* bp2 = (float*)(ws + 232209920);     //     1,280
  float* bp3 = (float*)(ws + 232211200);     //     1,280
  int* deg    = (int*)(ws + 232212480);      //   200,000
  float* dinv = (float*)(ws + 232412480);    //   200,000
  int* rowptr = (int*)(ws + 232612480);      //   200,004
  int* rptr2  = (int*)(ws + 232812484);      //   200,004
  int* bsum   = (int*)(ws + 233012488);      //       800
  int* bpre   = (int*)(ws + 233013288);      //       800
  int2* meta  = (int2*)(ws + 233014088);     // 4,800,000 -> total 237,814,088

  hipMemsetAsync(deg, 0, N_NODES * sizeof(int), stream);

  // merged setup: x convert + deg atomics + W^T + bias pads
  k_setup<<<68608, 256, 0, stream>>>(x, xh, W1, w1h, W2, w2h, W3, w3h,
                                     b2, bp2, b3, bp3, edst, deg);

  // multi-block scan + dinv
  k_scan1<<<196, 256, 0, stream>>>(deg, dinv, bsum, N_NODES);
  k_scan2<<<1, 256, 0, stream>>>(bsum, bpre, rowptr, 196, N_NODES);
  k_scan3<<<196, 256, 0, stream>>>(deg, bpre, rowptr, rptr2, N_NODES);
  k_fill<<<2344, 256, 0, stream>>>(esrc, edst, rptr2, meta, dinv, N_EDGES);

  // layer 1: h1 = xh @ W1 ; g1 = relu(agg(h1) + b1)   (grid: n fastest)
  gemm_f16_tn<<<dim3(4, 391), 256, 0, stream>>>(xh, w1h, h1, N_NODES, 512, 1280, 1280, 1280, 512);
  agg_relu3<512, 64, true, 0><<<12500, 256, 0, stream>>>(h1, rowptr, meta, dinv, b1, g1, N_NODES);

  // layer 2: h2 = g1 @ W2 (ldc=320, pad zeroed) ; g2 = relu(agg(h2) + bp2)
  gemm_f16_tn<<<dim3(3, 391), 256, 0, stream>>>(g1, w2h, h2, N_NODES, 300, 512, 512, 512, 320);
  agg_relu3<320, 40, true, 0><<<12500, 256, 0, stream>>>(h2, rowptr, meta, dinv, bp2, g2, N_NODES);

  // layer 3: h3 = g2 @ W3 (K=320 padded) ; out = relu(agg(h3) + bp3) fp32
  gemm_f16_tn<<<dim3(3, 391), 256, 0, stream>>>(g2, w3h, h3, N_NODES, 300, 320, 320, 320, 320);
  agg_relu3<320, 38, false, 300><<<12500, 256, 0, stream>>>(h3, rowptr, meta, dinv, bp3, out, N_NODES);
}

// Round 4
// 795.448 us; speedup vs baseline: 1.0379x; 1.0303x over previous
//
#include <hip/hip_runtime.h>

typedef _Float16 f16;
typedef _Float16 f16x2 __attribute__((ext_vector_type(2)));
typedef _Float16 f16x4 __attribute__((ext_vector_type(4)));
typedef _Float16 f16x8 __attribute__((ext_vector_type(8)));
typedef float f32x4 __attribute__((ext_vector_type(4)));

#define N_NODES 50000
#define N_EDGES 600000

// ---------- async global->LDS, 16B per lane ----------
__device__ __forceinline__ void gl_lds16(const void* g, void* l) {
  __builtin_amdgcn_global_load_lds(
      (__attribute__((address_space(1))) void*)(g),
      (__attribute__((address_space(3))) void*)(l), 16, 0, 0);
}

// ---------- merged setup: x->f16, deg atomics, W transposes, bias pads ----------
// grid layout (blocks of 256):
//   [0, 62500)        x convert (50000*1280/4 float4s, exact)
//   [62500, 64844)    deg atomics over 600000 edges
//   [64844, 67404)    W1^T  (655360 elems, exact)
//   [67404, 68004)    W2^T  (300 rows x 2 blocks)
//   [68004, 68604)    W3^T padded to 320 (300 rows x 2 blocks)
//   [68604, 68606)    bp2
//   [68606, 68608)    bp3
__global__ void k_setup(const float* __restrict__ x, f16* __restrict__ xh,
                        const float* __restrict__ W1, f16* __restrict__ w1h,
                        const float* __restrict__ W2, f16* __restrict__ w2h,
                        const float* __restrict__ W3, f16* __restrict__ w3h,
                        const float* __restrict__ b2, float* __restrict__ bp2,
                        const float* __restrict__ b3, float* __restrict__ bp3,
                        const int* __restrict__ edst, int* __restrict__ deg) {
  const int b = blockIdx.x, t = threadIdx.x;
  if (b < 62500) {
    long i = (long)b * 256 + t;
    float4 v = ((const float4*)x)[i];
    f16x4 o;
    o[0] = (f16)v.x; o[1] = (f16)v.y; o[2] = (f16)v.z; o[3] = (f16)v.w;
    ((f16x4*)xh)[i] = o;
  } else if (b < 64844) {
    int e = (b - 62500) * 256 + t;
    if (e < N_EDGES) atomicAdd(&deg[edst[e]], 1);
  } else if (b < 67404) {
    int idx = (b - 64844) * 256 + t;       // = n*1280 + k
    int n = idx / 1280, k = idx - n * 1280;
    w1h[idx] = (f16)W1[(size_t)k * 512 + n];
  } else if (b < 68004) {
    int bb = b - 67404;
    int n = bb >> 1, k = (bb & 1) * 256 + t;
    if (k < 512) w2h[(size_t)n * 512 + k] = (f16)W2[(size_t)k * 300 + n];
  } else if (b < 68604) {
    int bb = b - 68004;
    int n = bb >> 1, k = (bb & 1) * 256 + t;
    if (k < 320) w3h[(size_t)n * 320 + k] = (k < 300) ? (f16)W3[(size_t)k * 300 + n] : (f16)0.f;
  } else if (b < 68606) {
    int i = (b - 68604) * 256 + t;
    if (i < 320) bp2[i] = (i < 300) ? b2[i] : 0.f;
  } else {
    int i = (b - 68606) * 256 + t;
    if (i < 320) bp3[i] = (i < 300) ? b3[i] : 0.f;
  }
}

// ---------- multi-block exclusive scan of deg -> rowptr ----------
__device__ __forceinline__ int block_incl_scan256(int v, int t) {
  __shared__ int wsum[4];
  const int lane = t & 63, w = t >> 6;
  int incl = v;
#pragma unroll
  for (int off = 1; off < 64; off <<= 1) {
    int u = __shfl_up(incl, off, 64);
    if (lane >= off) incl += u;
  }
  if (lane == 63) wsum[w] = incl;
  __syncthreads();
  int add = 0;
#pragma unroll
  for (int k = 0; k < 4; ++k)
    if (k < w) add += wsum[k];
  return incl + add;
}

// per-block sums + dinv
__global__ void k_scan1(const int* __restrict__ deg, float* __restrict__ dinv,
                        int* __restrict__ bsum, int n) {
  __shared__ int ws4[4];
  const int t = threadIdx.x, b = blockIdx.x;
  const int i = b * 256 + t;
  int v = (i < n) ? deg[i] : 0;
  if (i < n) dinv[i] = rsqrtf((float)(v + 1));
  int s = v;
#pragma unroll
  for (int off = 1; off < 64; off <<= 1) s += __shfl_xor(s, off, 64);
  if ((t & 63) == 0) ws4[t >> 6] = s;
  __syncthreads();
  if (t == 0) bsum[b] = ws4[0] + ws4[1] + ws4[2] + ws4[3];
}

// scan the 196 block sums (single tiny block) + total -> rowptr[n]
__global__ void k_scan2(const int* __restrict__ bsum, int* __restrict__ bpre,
                        int* __restrict__ rowptr, int nb, int n) {
  const int t = threadIdx.x;
  int v = (t < nb) ? bsum[t] : 0;
  int incl = block_incl_scan256(v, t);
  if (t < nb) bpre[t] = incl - v;
  if (t == 255) rowptr[n] = incl;
}

// full exclusive positions; write rowptr and a second copy used as atomic cursor
__global__ void k_scan3(const int* __restrict__ deg, const int* __restrict__ bpre,
                        int* __restrict__ rowptr, int* __restrict__ rptr2, int n) {
  const int t = threadIdx.x, b = blockIdx.x;
  const int i = b * 256 + t;
  int v = (i < n) ? deg[i] : 0;
  int incl = block_incl_scan256(v, t);
  int ex = bpre[b] + incl - v;
  if (i < n) { rowptr[i] = ex; rptr2[i] = ex; }
}

// fill CSR: meta[pos] = {src, bitcast(norm)}; rptr2 doubles as cursor
__global__ void k_fill(const int* __restrict__ src, const int* __restrict__ dst,
                       int* __restrict__ rptr2, int2* __restrict__ meta,
                       const float* __restrict__ dinv, int E) {
  int e = blockIdx.x * 256 + threadIdx.x;
  if (e < E) {
    int d = dst[e], s = src[e];
    int pos = atomicAdd(&rptr2[d], 1);
    float w = dinv[s] * dinv[d];
    meta[pos] = make_int2(s, __float_as_int(w));
  }
}

// ---------- GEMM: C[M,N] = A[M,K] * B^T[N,K], f16 in, f16 out ----------
// 128x128 tile, BK=64, 4 waves (2x2 of 64x64), mfma_f32_16x16x32_f16
// Single-buffered m97-style 2-barrier loop, but:
//  * staging reads FULL 128B lines (8 rows x 128B per gl_lds16 call) -> no
//    half-line overfetch (old BK=32 read 64B segments = 2x HBM overfetch)
//  * 32 MFMAs amortize each barrier pair (was 16)
//  * bank-conflict fix per rule #21: LDS dest stays linear (gl_lds requires
//    it); the 16B-unit index of the GLOBAL source is pre-XORed with (row&7)
//    (a permutation WITHIN the 128B line, so fetch stays full-line), and the
//    ds_read applies the same XOR -> 2-way max (free, m136).
// zero-fills C cols in [N, ldc)
__global__ __launch_bounds__(256, 3)
void gemm_f16_tn(const f16* __restrict__ A, const f16* __restrict__ B,
                 f16* __restrict__ C, int M, int N, int K,
                 int lda, int ldb, int ldc) {
  __shared__ __align__(16) f16 As[128 * 64];   // 16 KiB
  __shared__ __align__(16) f16 Bs[128 * 64];   // 16 KiB
  const int tid = threadIdx.x;
  const int wave = tid >> 6;
  const int lane = tid & 63;
  const int bm = blockIdx.y, bn = blockIdx.x;

  // staging decomposition: call c in [0,4): row = wave*32 + c*8 + (lane>>3),
  // 16B-unit-in-row = (lane&7) ^ (lane>>3)   [row&7 == lane>>3]
  const int r8 = lane >> 3;                 // 0..7
  const int sunit = (lane & 7) ^ r8;        // XOR pre-swizzle of global src
  const char* aSrc[4];
  const char* bSrc[4];
#pragma unroll
  for (int c = 0; c < 4; ++c) {
    long ar = (long)bm * 128 + wave * 32 + c * 8 + r8; if (ar > M - 1) ar = M - 1;
    long br = (long)bn * 128 + wave * 32 + c * 8 + r8; if (br > N - 1) br = N - 1;
    aSrc[c] = (const char*)(A + ar * lda) + sunit * 16;
    bSrc[c] = (const char*)(B + br * ldb) + sunit * 16;
  }

  const int r16 = lane & 15;
  const int kq = lane >> 4;  // 0..3
  const int wm = wave & 1, wn = wave >> 1;

  // read offsets: frag t, k-slice ks: row = w*64 + t*16 + r16,
  // byte = row*128 + (((ks<<2)+kq) ^ (row&7))*16 ; row&7 == r16&7
  int aoff[4][2], boff[4][2];
#pragma unroll
  for (int t = 0; t < 4; ++t) {
#pragma unroll
    for (int ks = 0; ks < 2; ++ks) {
      int arow = wm * 64 + t * 16 + r16;
      aoff[t][ks] = arow * 128 + ((((ks << 2) + kq) ^ (arow & 7)) << 4);
      int brow = wn * 64 + t * 16 + r16;
      boff[t][ks] = brow * 128 + ((((ks << 2) + kq) ^ (brow & 7)) << 4);
    }
  }

  f32x4 acc[4][4] = {};

  for (int k0 = 0; k0 < K; k0 += 64) {
    __syncthreads();   // waves done reading LDS from previous iter
    const size_t kb = (size_t)k0 * 2;
#pragma unroll
    for (int c = 0; c < 4; ++c) {
      gl_lds16(aSrc[c] + kb, (char*)As + (wave * 32 + c * 8) * 128);
      gl_lds16(bSrc[c] + kb, (char*)Bs + (wave * 32 + c * 8) * 128);
    }
    __syncthreads();   // staging complete (compiler drains vmcnt before barrier)

#pragma unroll
    for (int ks = 0; ks < 2; ++ks) {
      f16x8 af[4], bf[4];
#pragma unroll
      for (int t = 0; t < 4; ++t) {
        af[t] = *(const f16x8*)((const char*)As + aoff[t][ks]);
        bf[t] = *(const f16x8*)((const char*)Bs + boff[t][ks]);
      }
#pragma unroll
      for (int mt = 0; mt < 4; ++mt)
#pragma unroll
        for (int nt = 0; nt < 4; ++nt)
          acc[mt][nt] = __builtin_amdgcn_mfma_f32_16x16x32_f16(af[mt], bf[nt], acc[mt][nt], 0, 0, 0);
    }
  }

  const int crow0 = bm * 128 + wm * 64;
  const int ccol0 = bn * 128 + wn * 64;
#pragma unroll
  for (int mt = 0; mt < 4; ++mt)
#pragma unroll
    for (int nt = 0; nt < 4; ++nt)
#pragma unroll
      for (int r = 0; r < 4; ++r) {
        int row = crow0 + mt * 16 + kq * 4 + r;
        int col = ccol0 + nt * 16 + r16;
        if (row < M && col < ldc)
          C[(size_t)row * ldc + col] = (col < N) ? (f16)acc[mt][nt][r] : (f16)0.f;
      }
}

// ---------- aggregation v3: wave-per-node, coalesced meta prefetch + shuffle bcast ----------
// out[n] = relu( dinv[n]^2*h[n] + sum_e w[e]*h[src[e]] + b )
template <int LDH, int ACT, bool F16OUT, int DOUT>
__global__ __launch_bounds__(256, 8)
void agg_relu3(const f16* __restrict__ h, const int* __restrict__ rowptr,
               const int2* __restrict__ meta, const float* __restrict__ dinv,
               const float* __restrict__ bias, void* __restrict__ outp, int nNodes) {
  const int tid = threadIdx.x;
  const int lane = tid & 63;
  const int node = blockIdx.x * 4 + (tid >> 6);
  if (node >= nNodes) return;
  const int r0 = __builtin_amdgcn_readfirstlane(rowptr[node]);
  const int r1 = __builtin_amdgcn_readfirstlane(rowptr[node + 1]);
  const float dv = __builtin_bit_cast(
      float, __builtin_amdgcn_readfirstlane(__builtin_bit_cast(int, dinv[node])));

  const int hoff = (lane < ACT ? lane : ACT - 1) * 8;
  const f16* hp = h + hoff;

  float acc[8];
  {
    f16x8 v = *(const f16x8*)(hp + (size_t)node * LDH);
    const float w0 = dv * dv;
#pragma unroll
    for (int j = 0; j < 8; ++j) acc[j] = w0 * (float)v[j];
  }

  for (int base = r0; base < r1; base += 64) {
    const int idx = base + lane;
    int2 m = (idx < r1) ? meta[idx] : make_int2(0, 0);
    const int cnt = min(64, r1 - base);
    int j = 0;
    for (; j + 2 <= cnt; j += 2) {
      int s0 = __shfl(m.x, j, 64);
      int s1 = __shfl(m.x, j + 1, 64);
      float w0 = __int_as_float(__shfl(m.y, j, 64));
      float w1 = __int_as_float(__shfl(m.y, j + 1, 64));
      f16x8 v0 = *(const f16x8*)(hp + (size_t)s0 * LDH);
      f16x8 v1 = *(const f16x8*)(hp + (size_t)s1 * LDH);
#pragma unroll
      for (int q = 0; q < 8; ++q) acc[q] = fmaf(w0, (float)v0[q], acc[q]);
#pragma unroll
      for (int q = 0; q < 8; ++q) acc[q] = fmaf(w1, (float)v1[q], acc[q]);
    }
    if (j < cnt) {
      int s0 = __shfl(m.x, j, 64);
      float w0 = __int_as_float(__shfl(m.y, j, 64));
      f16x8 v0 = *(const f16x8*)(hp + (size_t)s0 * LDH);
#pragma unroll
      for (int q = 0; q < 8; ++q) acc[q] = fmaf(w0, (float)v0[q], acc[q]);
    }
  }

  float4 bv0 = *(const float4*)(bias + hoff);
  float4 bv1 = *(const float4*)(bias + hoff + 4);
  float o[8];
  o[0] = fmaxf(acc[0] + bv0.x, 0.f); o[1] = fmaxf(acc[1] + bv0.y, 0.f);
  o[2] = fmaxf(acc[2] + bv0.z, 0.f); o[3] = fmaxf(acc[3] + bv0.w, 0.f);
  o[4] = fmaxf(acc[4] + bv1.x, 0.f); o[5] = fmaxf(acc[5] + bv1.y, 0.f);
  o[6] = fmaxf(acc[6] + bv1.z, 0.f); o[7] = fmaxf(acc[7] + bv1.w, 0.f);

  if constexpr (F16OUT) {
    if (lane < ACT) {
      f16x8 ov;
#pragma unroll
      for (int j = 0; j < 8; ++j) ov[j] = (f16)o[j];
      *(f16x8*)((f16*)outp + (size_t)node * LDH + lane * 8) = ov;
    }
  } else {
    float* orow = (float*)outp + (size_t)node * DOUT + lane * 8;
    if (lane * 8 + 4 <= DOUT)
      *(float4*)(orow) = make_float4(o[0], o[1], o[2], o[3]);
    if (lane * 8 + 8 <= DOUT)
      *(float4*)(orow + 4) = make_float4(o[4], o[5], o[6], o[7]);
  }
}

extern "C" void kernel_launch(void* const* d_in, const int* in_sizes, int n_in,
                              void* d_out, int out_size, void* d_ws, size_t ws_size,
                              hipStream_t stream) {
  const float* x  = (const float*)d_in[0];
  const float* W1 = (const float*)d_in[1];
  const float* b1 = (const float*)d_in[2];
  const float* W2 = (const float*)d_in[3];
  const float* b2 = (const float*)d_in[4];
  const float* W3 = (const float*)d_in[5];
  const float* b3 = (const float*)d_in[6];
  const int* eidx = (const int*)d_in[7];
  const int* esrc = eidx;
  const int* edst = eidx + N_EDGES;
  float* out = (float*)d_out;

  char* ws = (char*)d_ws;
  f16* xh = (f16*)(ws);                      // 50000*1280*2 = 128,000,000
  f16* h2 = (f16*)(ws);                      // 50000*320*2  =  32,000,000
  f16* g2 = (f16*)(ws + 32000000);           // 32,000,000
  f16* h3 = (f16*)(ws + 64000000);           // 32,000,000
  f16* h1 = (f16*)(ws + 128000000);          // 50000*512*2  =  51,200,000
  f16* g1 = (f16*)(ws + 179200000);          // 51,200,000
  f16* w1h = (f16*)(ws + 230400000);         // 1,310,720
  f16* w2h = (f16*)(ws + 231710720);         //   307,200
  f16* w3h = (f16*)(ws + 232017920);         //   192,000
  float* bp2 = (float*)(ws + 232209920);     //     1,280
  float* bp3 = (float*)(ws + 232211200);     //     1,280
  int* deg    = (int*)(ws + 232212480);      //   200,000
  float* dinv = (float*)(ws + 232412480);    //   200,000
  int* rowptr = (int*)(ws + 232612480);      //   200,004
  int* rptr2  = (int*)(ws + 232812484);      //   200,004
  int* bsum   = (int*)(ws + 233012488);      //       800
  int* bpre   = (int*)(ws + 233013288);      //       800
  int2* meta  = (int2*)(ws + 233014088);     // 4,800,000 -> total 237,814,088

  hipMemsetAsync(deg, 0, N_NODES * sizeof(int), stream);

  // merged setup: x convert + deg atomics + W^T + bias pads
  k_setup<<<68608, 256, 0, stream>>>(x, xh, W1, w1h, W2, w2h, W3, w3h,
                                     b2, bp2, b3, bp3, edst, deg);

  // multi-block scan + dinv
  k_scan1<<<196, 256, 0, stream>>>(deg, dinv, bsum, N_NODES);
  k_scan2<<<1, 256, 0, stream>>>(bsum, bpre, rowptr, 196, N_NODES);
  k_scan3<<<196, 256, 0, stream>>>(deg, bpre, rowptr, rptr2, N_NODES);
  k_fill<<<2344, 256, 0, stream>>>(esrc, edst, rptr2, meta, dinv, N_EDGES);

  // layer 1: h1 = xh @ W1 ; g1 = relu(agg(h1) + b1)   (grid: n fastest)
  gemm_f16_tn<<<dim3(4, 391), 256, 0, stream>>>(xh, w1h, h1, N_NODES, 512, 1280, 1280, 1280, 512);
  agg_relu3<512, 64, true, 0><<<12500, 256, 0, stream>>>(h1, rowptr, meta, dinv, b1, g1, N_NODES);

  // layer 2: h2 = g1 @ W2 (ldc=320, pad zeroed) ; g2 = relu(agg(h2) + bp2)
  gemm_f16_tn<<<dim3(3, 391), 256, 0, stream>>>(g1, w2h, h2, N_NODES, 300, 512, 512, 512, 320);
  agg_relu3<320, 40, true, 0><<<12500, 256, 0, stream>>>(h2, rowptr, meta, dinv, bp2, g2, N_NODES);

  // layer 3: h3 = g2 @ W3 (K=320 padded) ; out = relu(agg(h3) + bp3) fp32
  gemm_f16_tn<<<dim3(3, 391), 256, 0, stream>>>(g2, w3h, h3, N_NODES, 300, 320, 320, 320, 320);
  agg_relu3<320, 38, false, 300><<<12500, 256, 0, stream>>>(h3, rowptr, meta, dinv, bp3, out, N_NODES);
}